// Round 7
// baseline (195.294 us; speedup 1.0000x reference)
//
#include <hip/hip_runtime.h>
#include <math.h>
#include <stdint.h>

typedef __bf16 bf16_t;
typedef bf16_t bf16x8 __attribute__((ext_vector_type(8)));
typedef bf16_t bf16x4 __attribute__((ext_vector_type(4)));
typedef float  f32x4  __attribute__((ext_vector_type(4)));

#define MFMA16(a, b, c) __builtin_amdgcn_mfma_f32_16x16x32_bf16(a, b, c, 0, 0, 0)

constexpr float BN_INV = 0.999995000037499687f;  // 1/sqrt(1+1e-5)
constexpr int G2   = 2;    // point-groups (of 16) per wave in k2
constexpr int RECB = 80;   // record: [32 bf16 f | fp32 x,y,z | 4B pad]

// async global->LDS gather: per-lane global address, LDS dest = base + lane*16
__device__ __forceinline__ void agather16(const void* g, void* l) {
    __builtin_amdgcn_global_load_lds(
        (const __attribute__((address_space(1))) void*)g,
        (__attribute__((address_space(3))) void*)l, 16, 0, 0);
}

// ---------------------------------------------------------------------------
// K1: f = ReLU(BN(W2 @ feature)) -> packed 80B records; block 0 also writes
// the g-folded W3/W4 MFMA A-frag tables (read by k2 straight from L2).
// One wave per 64 points.
// ---------------------------------------------------------------------------
__global__ __launch_bounds__(256) void rfa_k1(
    const float* __restrict__ feature, const float* __restrict__ xyz,
    const float* __restrict__ W2, const float* __restrict__ g2, const float* __restrict__ b2,
    const float* __restrict__ W3, const float* __restrict__ g3,
    const float* __restrict__ W4, const float* __restrict__ g4,
    char* __restrict__ rec, bf16_t* __restrict__ gW3f, bf16_t* __restrict__ gW4f,
    int N, int nwaves)
{
    int tid = threadIdx.x;
    if (blockIdx.x == 0) {
        {   // W3 frag table: frag f (mt=f>>1, ks=f&1), entry per lane
            int f = tid >> 6, l = tid & 63;
            int h = (f >> 1) * 16 + (l & 15), ks = f & 1, q = l >> 4;
            float sc = g3[h] * BN_INV;
            const float* src = W3 + h * 64 + ks * 32 + q * 8;
            bf16x8 v;
            #pragma unroll
            for (int j = 0; j < 8; ++j) v[j] = (bf16_t)(src[j] * sc);
            *(bf16x8*)(gW3f + ((size_t)f * 64 + l) * 8) = v;
        }
        for (int s = tid; s < 512; s += 256) {  // W4 frag table (8 frags)
            int f = s >> 6, l = s & 63;
            int o = (f >> 1) * 16 + (l & 15), ks = f & 1, q = l >> 4;
            float sc = g4[o] * BN_INV;
            const float* src = W4 + o * 64 + ks * 32 + q * 8;
            bf16x8 v;
            #pragma unroll
            for (int j = 0; j < 8; ++j) v[j] = (bf16_t)(src[j] * sc);
            *(bf16x8*)(gW4f + ((size_t)f * 64 + l) * 8) = v;
        }
    }

    int gtid = blockIdx.x * 256 + tid;
    int w = gtid >> 6, lane = gtid & 63;
    if (w >= nwaves) return;
    int pt = lane & 15, quad = lane >> 4;
    int T0 = w * 64;
    int b  = T0 / N;
    int n0 = T0 - b * N;

    {   // xyz -> record tail (16B store: x,y,z + pad, bytes 64..80 of record)
        size_t p = (size_t)T0 + lane;
        float4 v = make_float4(xyz[p * 3], xyz[p * 3 + 1], xyz[p * 3 + 2], 0.f);
        *(float4*)(rec + p * RECB + 64) = v;
    }

    bf16x8 A[2][2];
    #pragma unroll
    for (int mt = 0; mt < 2; ++mt) {
        int h = mt * 16 + pt;
        float sc = g2[h] * BN_INV;
        #pragma unroll
        for (int ks = 0; ks < 2; ++ks) {
            const float* src = W2 + h * 64 + ks * 32 + quad * 8;
            bf16x8 v;
            #pragma unroll
            for (int j = 0; j < 8; ++j) v[j] = (bf16_t)(src[j] * sc);
            A[mt][ks] = v;
        }
    }
    float b2r[8];
    #pragma unroll
    for (int mt = 0; mt < 2; ++mt)
        #pragma unroll
        for (int r = 0; r < 4; ++r) b2r[mt * 4 + r] = b2[mt * 16 + quad * 4 + r];

    const float* fb = feature + (size_t)b * 64 * N;

    #pragma unroll
    for (int g = 0; g < 4; ++g) {
        int nn = n0 + g * 16 + pt;
        size_t T = (size_t)T0 + g * 16 + pt;
        bf16x8 Bf[2];
        #pragma unroll
        for (int ks = 0; ks < 2; ++ks) {
            bf16x8 v;
            #pragma unroll
            for (int j = 0; j < 8; ++j)
                v[j] = (bf16_t)fb[(size_t)(ks * 32 + quad * 8 + j) * N + nn];
            Bf[ks] = v;
        }
        f32x4 acc[2] = {f32x4{0,0,0,0}, f32x4{0,0,0,0}};
        #pragma unroll
        for (int mt = 0; mt < 2; ++mt) {
            acc[mt] = MFMA16(A[mt][0], Bf[0], acc[mt]);
            acc[mt] = MFMA16(A[mt][1], Bf[1], acc[mt]);
        }
        #pragma unroll
        for (int mt = 0; mt < 2; ++mt) {
            bf16x4 o;
            #pragma unroll
            for (int r = 0; r < 4; ++r)
                o[r] = (bf16_t)fmaxf(acc[mt][r] + b2r[mt * 4 + r], 0.f);
            *(bf16x4*)(rec + T * RECB + mt * 32 + quad * 8) = o;
        }
    }
}

// ---------------------------------------------------------------------------
// K2 (fused final conv): 16 points in columns, loop over 16 neighbors.
// Gathers are ASYNC (global_load_lds) into per-wave LDS slots: 4 pn-bufs
// (each serves 4 k's) + 4 rolling fj slots -> 8 loads in flight per wave at
// zero VGPR cost. Exact vmcnt discipline (loop body has no other vmem).
// No block barriers; W3/W4 frags come from global tables. XCD affinity kept.
// ---------------------------------------------------------------------------
__global__ __launch_bounds__(256) void rfa_k2(
    const char* __restrict__ rec, const int* __restrict__ nidx,
    const float* __restrict__ W1, const float* __restrict__ g1, const float* __restrict__ b1,
    const float* __restrict__ b3, const float* __restrict__ b4,
    const bf16_t* __restrict__ gW3f, const bf16_t* __restrict__ gW4f,
    float* __restrict__ out, int N)
{
    __shared__ __align__(16) char sAsync[4][8192];  // per wave: fj 4x1KB | pn 4x1KB

    int tid = threadIdx.x;
    int lane = tid & 63, wv = tid >> 6;
    int n = lane & 15, quad = lane >> 4;

    // batch->XCD affinity: blockIdx%8 ~ XCD; batch b owns XCDs {2b,2b+1}
    int blk  = blockIdx.x;
    int b    = (blk & 7) >> 1;
    int slot = (blk >> 3) * 2 + (blk & 1);
    int grp0 = slot * (4 * G2) + wv * G2;
    int base = b * N;

    // W3 A-frags from the prefolded table
    bf16x8 A3[2][2];
    #pragma unroll
    for (int mt = 0; mt < 2; ++mt)
        #pragma unroll
        for (int ks = 0; ks < 2; ++ks)
            A3[mt][ks] = *(const bf16x8*)(gW3f + ((size_t)(mt * 2 + ks) * 64 + lane) * 8);

    // W1 algebra constants (channels c = quad*8+j)
    float a8[8], V0[8], V1[8], V2[8];
    #pragma unroll
    for (int j = 0; j < 8; ++j) {
        int c = quad * 8 + j;
        float s1 = g1[c] * BN_INV;
        const float* wp = W1 + c * 10;
        a8[j] = wp[0] * s1;
        V0[j] = (wp[7] - wp[1]) * s1;
        V1[j] = (wp[8] - wp[2]) * s1;
        V2[j] = (wp[9] - wp[3]) * s1;
    }
    float b3r[8];
    #pragma unroll
    for (int mt = 0; mt < 2; ++mt)
        #pragma unroll
        for (int r = 0; r < 4; ++r) b3r[mt * 4 + r] = b3[mt * 16 + quad * 4 + r];

    const char* rb = rec + (size_t)base * RECB;
    char* fjs = &sAsync[wv][0];
    char* pns = &sAsync[wv][4096];

    for (int gi = 0; gi < G2; ++gi) {
        int grp  = grp0 + gi;
        int nloc = grp * 16;
        size_t tg = (size_t)base + nloc + n;

        float4 ps = *(const float4*)(rec + tg * RECB + 64);  // self xyz
        float hoist[8];
        #pragma unroll
        for (int j = 0; j < 8; ++j) {
            int c = quad * 8 + j;
            float s1 = g1[c] * BN_INV;
            const float* wp = W1 + c * 10;
            hoist[j] = b1[c] + ((wp[1] + wp[4]) * ps.x + (wp[2] + wp[5]) * ps.y +
                                (wp[3] + wp[6]) * ps.z) * s1;
        }

        // neighbor list for this lane's column (const-indexed for fj issues)
        int j16[16];
        #pragma unroll
        for (int q4 = 0; q4 < 4; ++q4) {
            int4 v = *(const int4*)(nidx + tg * 16 + q4 * 4);
            j16[q4 * 4 + 0] = v.x; j16[q4 * 4 + 1] = v.y;
            j16[q4 * 4 + 2] = v.z; j16[q4 * 4 + 3] = v.w;
        }
        // per-quad indices for the pn issues: lane (n,q) fetches k = kb*4+q
        int jq[4];
        #pragma unroll
        for (int kb = 0; kb < 4; ++kb)
            jq[kb] = nidx[tg * 16 + kb * 4 + quad];

        // clean vmem baseline: everything older (incl. prev epilogue stores,
        // the self/idx loads above) drains; loop counts are then exact.
        asm volatile("s_waitcnt vmcnt(0)" ::: "memory");

        // prologue: 4 pn-bufs (each covers 4 k's) + fj slots 0..3
        #pragma unroll
        for (int kb = 0; kb < 4; ++kb)
            agather16(rb + (size_t)jq[kb] * RECB + 64, pns + kb * 1024 + lane * 16);
        #pragma unroll
        for (int k0 = 0; k0 < 4; ++k0)
            agather16(rb + (size_t)j16[k0] * RECB + quad * 16, fjs + k0 * 1024 + lane * 16);

        f32x4 mx0 = {-3.0e38f, -3.0e38f, -3.0e38f, -3.0e38f};
        f32x4 mx1 = {-3.0e38f, -3.0e38f, -3.0e38f, -3.0e38f};

        #pragma unroll
        for (int k = 0; k < 16; ++k) {
            // wait until fj[k] (and, transitively, all pn) has landed in LDS
            if (k <= 12)      asm volatile("s_waitcnt vmcnt(3)" ::: "memory");
            else if (k == 13) asm volatile("s_waitcnt vmcnt(2)" ::: "memory");
            else if (k == 14) asm volatile("s_waitcnt vmcnt(1)" ::: "memory");
            else              asm volatile("s_waitcnt vmcnt(0)" ::: "memory");

            bf16x8 Bj = *(const bf16x8*)(fjs + (k & 3) * 1024 + lane * 16);
            f32x4  p4 = *(const f32x4*)(pns + (k >> 2) * 1024 + ((k & 3) * 16 + n) * 16);
            asm volatile("s_waitcnt lgkmcnt(0)" ::: "memory");  // data in regs; slot reusable

            if (k + 4 < 16)
                agather16(rb + (size_t)j16[k + 4] * RECB + quad * 16,
                          fjs + (k & 3) * 1024 + lane * 16);

            float rx = ps.x - p4[0], ry = ps.y - p4[1], rz = ps.z - p4[2];
            float dist = sqrtf(rx * rx + ry * ry + rz * rz);

            bf16x8 Bx;
            #pragma unroll
            for (int c = 0; c < 8; ++c) {
                float v = fmaf(a8[c], dist, hoist[c]);
                v = fmaf(V0[c], p4[0], v);
                v = fmaf(V1[c], p4[1], v);
                v = fmaf(V2[c], p4[2], v);
                Bx[c] = (bf16_t)fmaxf(v, 0.f);
            }

            f32x4 ac0 = {0,0,0,0}, ac1 = {0,0,0,0};
            ac0 = MFMA16(A3[0][0], Bj, ac0);
            ac0 = MFMA16(A3[0][1], Bx, ac0);
            ac1 = MFMA16(A3[1][0], Bj, ac1);
            ac1 = MFMA16(A3[1][1], Bx, ac1);
            #pragma unroll
            for (int r = 0; r < 4; ++r) {
                mx0[r] = fmaxf(mx0[r], ac0[r]);
                mx1[r] = fmaxf(mx1[r], ac1[r]);
            }
        }

        // epilogue: bias+ReLU on max -> bounce (pn region, now idle) -> W4 MFMA
        float* bounce = (float*)pns;  // 32x18 floats = 2304B < 4KB
        #pragma unroll
        for (int r = 0; r < 4; ++r) {
            bounce[(quad * 4 + r) * 18 + n]      = fmaxf(mx0[r] + b3r[r], 0.f);
            bounce[(16 + quad * 4 + r) * 18 + n] = fmaxf(mx1[r] + b3r[4 + r], 0.f);
        }
        asm volatile("s_waitcnt lgkmcnt(0)" ::: "memory");
        bf16x8 Bm;
        #pragma unroll
        for (int jj = 0; jj < 8; ++jj)
            Bm[jj] = (bf16_t)bounce[(quad * 8 + jj) * 18 + n];

        bf16x8 Bs = *(const bf16x8*)(rec + tg * RECB + quad * 16);  // f_self

        #pragma unroll
        for (int mt = 0; mt < 4; ++mt) {
            bf16x8 A40 = *(const bf16x8*)(gW4f + ((size_t)(mt * 2 + 0) * 64 + lane) * 8);
            bf16x8 A41 = *(const bf16x8*)(gW4f + ((size_t)(mt * 2 + 1) * 64 + lane) * 8);
            float4 bv  = *(const float4*)(b4 + mt * 16 + quad * 4);
            f32x4 acc = {0,0,0,0};
            acc = MFMA16(A40, Bm, acc);
            acc = MFMA16(A41, Bs, acc);
            out[((size_t)b * 64 + mt * 16 + quad * 4 + 0) * N + nloc + n] = fmaxf(acc[0] + bv.x, 0.f);
            out[((size_t)b * 64 + mt * 16 + quad * 4 + 1) * N + nloc + n] = fmaxf(acc[1] + bv.y, 0.f);
            out[((size_t)b * 64 + mt * 16 + quad * 4 + 2) * N + nloc + n] = fmaxf(acc[2] + bv.z, 0.f);
            out[((size_t)b * 64 + mt * 16 + quad * 4 + 3) * N + nloc + n] = fmaxf(acc[3] + bv.w, 0.f);
        }
        asm volatile("s_waitcnt lgkmcnt(0)" ::: "memory");  // bounce reads done before reuse
    }
}

// ---------------------------------------------------------------------------
extern "C" void kernel_launch(void* const* d_in, const int* in_sizes, int n_in,
                              void* d_out, int out_size, void* d_ws, size_t ws_size,
                              hipStream_t stream) {
    const float* feature = (const float*)d_in[0];
    const float* xyz     = (const float*)d_in[1];
    const int*   nidx    = (const int*)  d_in[2];
    const float* W1      = (const float*)d_in[3];
    const float* W2      = (const float*)d_in[4];
    const float* W3      = (const float*)d_in[5];
    const float* W4      = (const float*)d_in[6];
    const float* g1 = (const float*)d_in[7];
    const float* b1 = (const float*)d_in[8];
    const float* g2 = (const float*)d_in[9];
    const float* b2 = (const float*)d_in[10];
    const float* g3 = (const float*)d_in[11];
    const float* b3 = (const float*)d_in[12];
    const float* g4 = (const float*)d_in[13];
    const float* b4 = (const float*)d_in[14];
    float* out = (float*)d_out;

    const int B = 4;
    const int N = in_sizes[1] / (B * 3);
    const int total = B * N;                       // 163840

    char*   rec  = (char*)d_ws;                    // 80B * total = 13.1 MB
    bf16_t* gW3f = (bf16_t*)(rec + (size_t)total * RECB);          // 4 KB
    bf16_t* gW4f = gW3f + 4 * 64 * 8;                              // 8 KB

    const int nw1  = total / 64;
    const int blk1 = (nw1 + 3) / 4;
    const int blk2 = total / (64 * G2);            // 1280, divisible by 8

    rfa_k1<<<blk1, 256, 0, stream>>>(feature, xyz, W2, g2, b2, W3, g3, W4, g4,
                                     rec, gW3f, gW4f, N, nw1);
    rfa_k2<<<blk2, 256, 0, stream>>>(rec, nidx, W1, g1, b1, b3, b4,
                                     gW3f, gW4f, out, N);
}